// Round 7
// baseline (220.774 us; speedup 1.0000x reference)
//
#include <hip/hip_runtime.h>

typedef float f32x4 __attribute__((ext_vector_type(4)));
typedef __bf16 bf16x8 __attribute__((ext_vector_type(8)));

static __device__ __forceinline__ unsigned short f2bf(float f) {
    unsigned int u = __builtin_bit_cast(unsigned int, f);
    u += 0x7fffu + ((u >> 16) & 1u);
    return (unsigned short)(u >> 16);
}
static __device__ __forceinline__ unsigned short bfc(float f) {
    return __builtin_bit_cast(unsigned short, (__bf16)f);
}

#define QSC 0.18033688011112042f   // log2(e)/sqrt(HD) folded into Q

typedef const __attribute__((address_space(1))) unsigned int gu32;
typedef __attribute__((address_space(3))) unsigned int lu32;
static __device__ __forceinline__ void gload_lds16(const unsigned short* g, unsigned short* l) {
    __builtin_amdgcn_global_load_lds((gu32*)g, (lu32*)l, 16, 0, 0);
}
static __device__ __forceinline__ void sbar() {
    __builtin_amdgcn_sched_barrier(0);
    __builtin_amdgcn_s_barrier();
    __builtin_amdgcn_sched_barrier(0);
}

// ---------------- fp32 -> bf16 elementwise convert ----------------
__global__ __launch_bounds__(256)
void cvt_bf16(const float* __restrict__ in, unsigned short* __restrict__ out) {
    int i = blockIdx.x * 256 + threadIdx.x;
    const float4* p = (const float4*)in + (size_t)i * 2;
    float4 a = p[0], b = p[1];
    union { unsigned short s[8]; uint4 v; } u;
    u.s[0] = f2bf(a.x); u.s[1] = f2bf(a.y); u.s[2] = f2bf(a.z); u.s[3] = f2bf(a.w);
    u.s[4] = f2bf(b.x); u.s[5] = f2bf(b.y); u.s[6] = f2bf(b.z); u.s[7] = f2bf(b.w);
    ((uint4*)out)[i] = u.v;
}

// ---------------- weight transpose+convert: w[K][N] fp32 -> wT[N][K] bf16 ----------------
__global__ __launch_bounds__(256)
void transpose_w(const float* __restrict__ w, unsigned short* __restrict__ wT,
                 int K, int N) {
    __shared__ unsigned short Lt[64][65];
    const int k0 = blockIdx.x * 64, n0 = blockIdx.y * 64;
    const int t = threadIdx.x;
    const int r = t >> 4, c4 = (t & 15) * 4;
    #pragma unroll
    for (int i = 0; i < 4; i++) {
        int rr = r + i * 16;
        float4 v = *(const float4*)(w + (k0 + rr) * N + n0 + c4);
        Lt[rr][c4 + 0] = f2bf(v.x); Lt[rr][c4 + 1] = f2bf(v.y);
        Lt[rr][c4 + 2] = f2bf(v.z); Lt[rr][c4 + 3] = f2bf(v.w);
    }
    __syncthreads();
    const int rn = t >> 3, ks = (t & 7) * 8;
    #pragma unroll
    for (int i = 0; i < 2; i++) {
        int rr = rn + i * 32;
        unsigned short tmp[8];
        #pragma unroll
        for (int j = 0; j < 8; j++) tmp[j] = Lt[ks + j][rr];
        *(uint4*)(wT + (n0 + rr) * K + k0 + ks) = *(const uint4*)tmp;
    }
}

// ---------------- QKV GEMM: 256x256 tile, BK=64, 8-phase counted-vmcnt ----------------
// A[8192][1024] bf16, Bt[3072][1024] bf16. LDS 128KB, swizzled (both-sides XOR).
#define GK 1024
#define NT 16   // K / 64

__global__ __launch_bounds__(512, 2)
void qkv_gemm3(const unsigned short* __restrict__ A,
               const unsigned short* __restrict__ Bt,
               const float* __restrict__ bias,
               unsigned short* __restrict__ q_ws,
               unsigned short* __restrict__ k_ws,
               unsigned short* __restrict__ vT_ws)
{
    __shared__ unsigned short L[2][2][16384];   // [dbuf][A/B][256 rows x 64] = 128 KiB
    const int tid = threadIdx.x;
    const int lane = tid & 63, w = tid >> 6;        // 8 waves
    const int l15 = lane & 15, lhi = lane >> 4;
    const int m0 = blockIdx.x * 256, n0 = blockIdx.y * 256;
    const int wr = w >> 2, wc = w & 3;              // wave grid 2M x 4N

    // --- staging geometry: half-tile = 128 rows x 64 cols = 2 gload_lds/thread
    // lane chunk j: row = j*64 + w*8 + (lane>>3), col elems = (lane&7)*8
    // swizzle v(row) = (row>>1)&3, source col ^= v<<3 (linear LDS dest)
    const int srow0 = w * 8 + (lane >> 3);
    const int selem = ((lane & 7) * 8) ^ (((srow0 >> 1) & 3) << 3);
    const unsigned short* gA0 = A  + (size_t)(m0 + srow0) * GK + selem;
    const unsigned short* gB0 = Bt + (size_t)(n0 + srow0) * GK + selem;

    // op: 0=A 1=B ; h: half ; bufi ; kt: K-tile index
    #define STAGE(op, h, bufi, kt) do { \
        const unsigned short* _s = ((op) ? gB0 : gA0) + (size_t)(h) * 128 * GK + (kt) * 64; \
        unsigned short* _d = &L[bufi][op][(h) * 8192 + w * 512]; \
        gload_lds16(_s, _d); \
        gload_lds16(_s + 64 * GK, _d + 4096); \
    } while (0)

    // --- fragment-read geometry (same swizzle on read)
    const int vsw = ((l15 >> 1) & 3) << 3;
    const int c0 = (lhi * 8) ^ vsw;
    const int c1 = (32 + lhi * 8) ^ vsw;
    const int arb = (wr * 128 + l15) * 64;
    const int brb = (wc * 64 + l15) * 64;

    f32x4 acc[8][4] = {};

    // --- prologue: t0 full + t1 B-halves; vmcnt(4) => t0 landed
    STAGE(0, 0, 0, 0); STAGE(0, 1, 0, 0); STAGE(1, 0, 0, 0); STAGE(1, 1, 0, 0);
    STAGE(1, 0, 1, 1); STAGE(1, 1, 1, 1);
    asm volatile("s_waitcnt vmcnt(4)" ::: "memory");
    sbar();

    for (int t = 0; t < NT; ++t) {
        const int buf = t & 1;
        const unsigned short* La = &L[buf][0][0];
        const unsigned short* Lb = &L[buf][1][0];
        bf16x8 aq[4][2], b0q[2][2], b1q[2][2];

        // ---- P1: reads A(qm0) 8 + B(qn1) 4 ; stage A0(t+1) -> buf^1
        #pragma unroll
        for (int f = 0; f < 4; ++f) {
            aq[f][0] = *(const bf16x8*)&La[arb + f * 1024 + c0];
            aq[f][1] = *(const bf16x8*)&La[arb + f * 1024 + c1];
        }
        #pragma unroll
        for (int g = 0; g < 2; ++g) {
            b1q[g][0] = *(const bf16x8*)&Lb[brb + (2 + g) * 1024 + c0];
            b1q[g][1] = *(const bf16x8*)&Lb[brb + (2 + g) * 1024 + c1];
        }
        if (t + 1 < NT) STAGE(0, 0, buf ^ 1, t + 1);
        sbar();
        __builtin_amdgcn_s_setprio(1);
        #pragma unroll
        for (int f = 0; f < 4; ++f)
            #pragma unroll
            for (int g = 0; g < 2; ++g) {
                acc[f][2 + g] = __builtin_amdgcn_mfma_f32_16x16x32_bf16(aq[f][0], b1q[g][0], acc[f][2 + g], 0, 0, 0);
                acc[f][2 + g] = __builtin_amdgcn_mfma_f32_16x16x32_bf16(aq[f][1], b1q[g][1], acc[f][2 + g], 0, 0, 0);
            }
        __builtin_amdgcn_s_setprio(0);
        sbar();

        // ---- P2: reads B(qn0) 4 ; stage A1(t+1) -> buf^1
        #pragma unroll
        for (int g = 0; g < 2; ++g) {
            b0q[g][0] = *(const bf16x8*)&Lb[brb + g * 1024 + c0];
            b0q[g][1] = *(const bf16x8*)&Lb[brb + g * 1024 + c1];
        }
        if (t + 1 < NT) STAGE(0, 1, buf ^ 1, t + 1);
        sbar();
        __builtin_amdgcn_s_setprio(1);
        #pragma unroll
        for (int f = 0; f < 4; ++f)
            #pragma unroll
            for (int g = 0; g < 2; ++g) {
                acc[f][g] = __builtin_amdgcn_mfma_f32_16x16x32_bf16(aq[f][0], b0q[g][0], acc[f][g], 0, 0, 0);
                acc[f][g] = __builtin_amdgcn_mfma_f32_16x16x32_bf16(aq[f][1], b0q[g][1], acc[f][g], 0, 0, 0);
            }
        __builtin_amdgcn_s_setprio(0);
        sbar();

        // ---- P3: reads A(qm1) 8 ; stage B0(t+2) -> buf (B reads of tile t done at P2)
        #pragma unroll
        for (int f = 0; f < 4; ++f) {
            aq[f][0] = *(const bf16x8*)&La[arb + (4 + f) * 1024 + c0];
            aq[f][1] = *(const bf16x8*)&La[arb + (4 + f) * 1024 + c1];
        }
        if (t + 2 < NT) STAGE(1, 0, buf, t + 2);
        sbar();
        __builtin_amdgcn_s_setprio(1);
        #pragma unroll
        for (int f = 0; f < 4; ++f)
            #pragma unroll
            for (int g = 0; g < 2; ++g) {
                acc[4 + f][g] = __builtin_amdgcn_mfma_f32_16x16x32_bf16(aq[f][0], b0q[g][0], acc[4 + f][g], 0, 0, 0);
                acc[4 + f][g] = __builtin_amdgcn_mfma_f32_16x16x32_bf16(aq[f][1], b0q[g][1], acc[4 + f][g], 0, 0, 0);
            }
        __builtin_amdgcn_s_setprio(0);
        sbar();

        // ---- P4: no reads ; stage B1(t+2) -> buf ; counted vmcnt(4) => tile t+1 landed
        if (t + 2 < NT) STAGE(1, 1, buf, t + 2);
        asm volatile("s_waitcnt vmcnt(4)" ::: "memory");
        sbar();
        __builtin_amdgcn_s_setprio(1);
        #pragma unroll
        for (int f = 0; f < 4; ++f)
            #pragma unroll
            for (int g = 0; g < 2; ++g) {
                acc[4 + f][2 + g] = __builtin_amdgcn_mfma_f32_16x16x32_bf16(aq[f][0], b1q[g][0], acc[4 + f][2 + g], 0, 0, 0);
                acc[4 + f][2 + g] = __builtin_amdgcn_mfma_f32_16x16x32_bf16(aq[f][1], b1q[g][1], acc[4 + f][2 + g], 0, 0, 0);
            }
        __builtin_amdgcn_s_setprio(0);
        sbar();
    }
    #undef STAGE

    // --- epilogue: bias + QKV scatter (Q scaled, V transposed)
    #pragma unroll
    for (int g = 0; g < 4; ++g) {
        int col = n0 + wc * 64 + g * 16 + l15;
        float bv = bias[col];
        int which = col >> 10;          // 0=Q 1=K 2=V
        int d = col & 1023;
        int h = d >> 6, hd = d & 63;
        int bhc = h;                     // completed with b below
        #pragma unroll
        for (int f = 0; f < 8; ++f) {
            #pragma unroll
            for (int j = 0; j < 4; ++j) {
                int row = m0 + wr * 128 + f * 16 + lhi * 4 + j;
                int b = row >> 11, tt = row & 2047;
                float val = acc[f][g][j] + bv;
                int bh = b * 16 + bhc;
                if (which == 0)      q_ws[(bh * 2048 + tt) * 64 + hd] = f2bf(val * QSC);
                else if (which == 1) k_ws[(bh * 2048 + tt) * 64 + hd] = f2bf(val);
                else                 vT_ws[(bh * 64 + hd) * 2048 + tt] = f2bf(val);
            }
        }
    }
}

// ---------------- Flash attention (causal) ----------------
#define LKK 72

__global__ __launch_bounds__(512, 4)
void attn_fwd(const unsigned short* __restrict__ q_ws,
              const unsigned short* __restrict__ k_ws,
              const unsigned short* __restrict__ vT_ws,
              unsigned short* __restrict__ attn_ws)
{
    __shared__ unsigned short Kb[2][64 * LKK];
    __shared__ unsigned short Vb[2][64 * LKK];
    __shared__ unsigned short Pl[8][16 * 64];

    const int bh = blockIdx.x;
    const int p  = blockIdx.y;
    const int b = bh >> 4, h = bh & 15;
    const int tid = threadIdx.x;
    const int lane = tid & 63, wid = tid >> 6;
    const int l15 = lane & 15, lhi = lane >> 4;
    const int tbase = bh * 2048;
    const float NINF = -__builtin_inff();

    const int r0 = tid >> 3;
    const int c0 = (tid & 7) * 8;
    const unsigned short* kg = k_ws + (size_t)(tbase + r0) * 64 + c0;
    const unsigned short* vg = vT_ws + ((size_t)bh * 64 + r0) * 2048 + c0;

    unsigned short* Pw = &Pl[wid][0];
    const int xr = l15 & 7;

    #pragma unroll 1
    for (int seg = 0; seg < 2; ++seg) {
        const int qb = seg ? p : 15 - p;
        const int q0 = qb * 128;
        const int qrow = q0 + wid * 16;
        const int nkv = 2 * (qb + 1);

        bf16x8 qf[2];
        #pragma unroll
        for (int ks = 0; ks < 2; ks++)
            qf[ks] = *(const bf16x8*)(q_ws + (size_t)(tbase + qrow + l15) * 64 + ks * 32 + lhi * 8);

        f32x4 o[4] = {};
        float mreg = NINF, lst = 0.f;

        {
            uint4 ka = *(const uint4*)(kg);
            uint4 va = *(const uint4*)(vg);
            *(uint4*)(&Kb[0][r0 * LKK + c0]) = ka;
            *(uint4*)(&Vb[0][r0 * LKK + c0]) = va;
        }
        __syncthreads();

        int cur = 0;
        for (int kb = 0; kb < nkv; ++kb) {
            const int k0 = kb * 64;
            const int knx = (kb + 1 < nkv ? kb + 1 : kb) * 64;
            uint4 ka = *(const uint4*)(kg + (size_t)knx * 64);
            uint4 va = *(const uint4*)(vg + knx);

            if (k0 <= qrow + 15) {
                f32x4 s[4] = {};
                __builtin_amdgcn_s_setprio(1);
                #pragma unroll
                for (int ks = 0; ks < 2; ks++) {
                    bf16x8 kf[4];
                    #pragma unroll
                    for (int n = 0; n < 4; n++)
                        kf[n] = *(const bf16x8*)(&Kb[cur][(n * 16 + l15) * LKK + ks * 32 + lhi * 8]);
                    #pragma unroll
                    for (int n = 0; n < 4; n++)
                        s[n] = __builtin_amdgcn_mfma_f32_16x16x32_bf16(kf[n], qf[ks], s[n], 0, 0, 0);
                }
                __builtin_amdgcn_s_setprio(0);
                if (k0 + 63 > qrow) {
                    int qg = qrow + l15;
                    #pragma unroll
                    for (int n = 0; n < 4; n++) {
                        int kgl = k0 + n * 16 + lhi * 4;
                        #pragma unroll
                        for (int j = 0; j < 4; j++)
                            s[n][j] = (kgl + j <= qg) ? s[n][j] : NINF;
                    }
                }
                float mx = NINF;
                #pragma unroll
                for (int n = 0; n < 4; n++)
                    #pragma unroll
                    for (int j = 0; j < 4; j++)
                        mx = fmaxf(mx, s[n][j]);
                mx = fmaxf(mx, __shfl_xor(mx, 16));
                mx = fmaxf(mx, __shfl_xor(mx, 32));

                if (__all(mx <= mreg + 8.f)) {
                    float rs = 0.f;
                    #pragma unroll
                    for (int n = 0; n < 4; n++)
                        #pragma unroll
                        for (int j = 0; j < 4; j++) {
                            float pv = exp2f(s[n][j] - mreg);
                            s[n][j] = pv;
                            rs += pv;
                        }
                    rs += __shfl_xor(rs, 16);
                    rs += __shfl_xor(rs, 32);
                    lst += rs;
                } else {
                    float mnew = fmaxf(mreg, mx);
                    float al = exp2f(mreg - mnew);
                    mreg = mnew;
                    float rs = 0.f;
                    #pragma unroll
                    for (int n = 0; n < 4; n++)
                        #pragma unroll
                        for (int j = 0; j < 4; j++) {
                            float pv = exp2f(s[n][j] - mnew);
                            s[n][j] = pv;
                            rs += pv;
                        }
                    rs += __shfl_xor(rs, 16);
                    rs += __shfl_xor(rs, 32);
                    lst = lst * al + rs;
                    #pragma unroll
                    for (int j = 0; j < 4; j++) {
                        float a = __shfl(al, lhi * 4 + j);
                        #pragma unroll
                        for (int nd = 0; nd < 4; nd++)
                            o[nd][j] *= a;
                    }
                }
                #pragma unroll
                for (int n = 0; n < 4; n++) {
                    ushort4 pk;
                    pk.x = bfc(s[n][0]); pk.y = bfc(s[n][1]);
                    pk.z = bfc(s[n][2]); pk.w = bfc(s[n][3]);
                    int chunk = (2 * n + (lhi >> 1)) ^ xr;
                    *(ushort4*)(&Pw[l15 * 64 + chunk * 8 + (lhi & 1) * 4]) = pk;
                }
                __builtin_amdgcn_s_setprio(1);
                #pragma unroll
                for (int ks = 0; ks < 2; ks++) {
                    int chunk = (4 * ks + lhi) ^ xr;
                    bf16x8 pf = *(const bf16x8*)(&Pw[l15 * 64 + chunk * 8]);
                    bf16x8 vf[4];
                    #pragma unroll
                    for (int nd = 0; nd < 4; nd++)
                        vf[nd] = *(const bf16x8*)(&Vb[cur][(nd * 16 + l15) * LKK + ks * 32 + lhi * 8]);
                    #pragma unroll
                    for (int nd = 0; nd < 4; nd++)
                        o[nd] = __builtin_amdgcn_mfma_f32_16x16x32_bf16(pf, vf[nd], o[nd], 0, 0, 0);
                }
                __builtin_amdgcn_s_setprio(0);
            }
            *(uint4*)(&Kb[cur ^ 1][r0 * LKK + c0]) = ka;
            *(uint4*)(&Vb[cur ^ 1][r0 * LKK + c0]) = va;
            __syncthreads();
            cur ^= 1;
        }
        #pragma unroll
        for (int j = 0; j < 4; j++) {
            float lv = __shfl(lst, lhi * 4 + j);
            float inv = 1.0f / lv;
            int t = qrow + lhi * 4 + j;
            #pragma unroll
            for (int nd = 0; nd < 4; nd++) {
                int d = nd * 16 + l15;
                attn_ws[((size_t)(b * 2048 + t) * 16 + h) * 64 + d] = f2bf(o[nd][j] * inv);
            }
        }
    }
}

// ---------------- Output projection GEMM (2-phase prefetch pipeline) ----------------
__global__ __launch_bounds__(256)
void proj_gemm2(const unsigned short* __restrict__ A,
                const unsigned short* __restrict__ Bt,
                const float* __restrict__ bias, float* __restrict__ out)
{
    const int K = 1024, N = 1024;
    __shared__ unsigned short Al[2][128 * 32];
    __shared__ unsigned short Bl[2][128 * 32];
    const int tid = threadIdx.x;
    const int lane = tid & 63, w = tid >> 6;
    const int l15 = lane & 15, lhi = lane >> 4;
    const int m0 = blockIdx.x * 128, n0 = blockIdx.y * 128;
    const int wm = (w >> 1) * 64, wn = (w & 1) * 64;

    const int srow = w * 32 + (lane >> 2);
    const int sslot = lane & 3;
    const unsigned short* ga = A + (size_t)(m0 + srow) * K + sslot * 8;
    const unsigned short* gb = Bt + (size_t)(n0 + srow) * K + sslot * 8;
    const int lofs = w * 32 * 32;

    f32x4 acc[4][4] = {};

    gload_lds16(ga, &Al[0][lofs]);
    gload_lds16(ga + 16 * K, &Al[0][lofs + 512]);
    gload_lds16(gb, &Bl[0][lofs]);
    gload_lds16(gb + 16 * K, &Bl[0][lofs + 512]);
    __syncthreads();

    int cur = 0;
    for (int k0 = 0; k0 < K; k0 += 32) {
        const int nxt = cur ^ 1;
        if (k0 + 32 < K) {
            gload_lds16(ga + k0 + 32,          &Al[nxt][lofs]);
            gload_lds16(ga + k0 + 32 + 16 * K, &Al[nxt][lofs + 512]);
            gload_lds16(gb + k0 + 32,          &Bl[nxt][lofs]);
            gload_lds16(gb + k0 + 32 + 16 * K, &Bl[nxt][lofs + 512]);
        }
        bf16x8 af[4], bfr[4];
        #pragma unroll
        for (int m = 0; m < 4; m++)
            af[m] = *(const bf16x8*)(&Al[cur][(wm + m * 16 + l15) * 32 + lhi * 8]);
        #pragma unroll
        for (int n = 0; n < 4; n++)
            bfr[n] = *(const bf16x8*)(&Bl[cur][(wn + n * 16 + l15) * 32 + lhi * 8]);
        __builtin_amdgcn_s_setprio(1);
        #pragma unroll
        for (int m = 0; m < 4; m++)
            #pragma unroll
            for (int n = 0; n < 4; n++)
                acc[m][n] = __builtin_amdgcn_mfma_f32_16x16x32_bf16(af[m], bfr[n], acc[m][n], 0, 0, 0);
        __builtin_amdgcn_s_setprio(0);
        __syncthreads();
        cur = nxt;
    }

    #pragma unroll
    for (int n = 0; n < 4; n++) {
        int col = n0 + wn + n * 16 + l15;
        float bv = bias[col];
        #pragma unroll
        for (int m = 0; m < 4; m++)
            #pragma unroll
            for (int j = 0; j < 4; j++) {
                int row = m0 + wm + m * 16 + lhi * 4 + j;
                out[row * N + col] = acc[m][n][j] + bv;
            }
    }
}

extern "C" void kernel_launch(void* const* d_in, const int* in_sizes, int n_in,
                              void* d_out, int out_size, void* d_ws, size_t ws_size,
                              hipStream_t stream)
{
    const float* x      = (const float*)d_in[0];
    const float* w_qkv  = (const float*)d_in[1];
    const float* b_qkv  = (const float*)d_in[2];
    const float* w_proj = (const float*)d_in[3];
    const float* b_proj = (const float*)d_in[4];
    float* out = (float*)d_out;

    const size_t SEG = (size_t)8 * 1024 * 1024;
    unsigned short* q_ws    = (unsigned short*)d_ws;
    unsigned short* k_ws    = q_ws + SEG;
    unsigned short* vT_ws   = k_ws + SEG;
    unsigned short* attn_ws = vT_ws + SEG;

    unsigned short* x_bf   = (unsigned short*)d_out;          // d_out as scratch
    unsigned short* wqkvT  = x_bf + SEG;
    unsigned short* wprojT = q_ws;                            // dead after attn

    cvt_bf16<<<4096, 256, 0, stream>>>(x, x_bf);
    transpose_w<<<dim3(16, 48), 256, 0, stream>>>(w_qkv, wqkvT, 1024, 3072);
    qkv_gemm3<<<dim3(32, 12), 512, 0, stream>>>(x_bf, wqkvT, b_qkv, q_ws, k_ws, vT_ws);
    attn_fwd<<<dim3(64, 8), 512, 0, stream>>>(q_ws, k_ws, vT_ws, attn_ws);
    transpose_w<<<dim3(16, 16), 256, 0, stream>>>(w_proj, wprojT, 1024, 1024);
    proj_gemm2<<<dim3(64, 8), 256, 0, stream>>>(attn_ws, wprojT, b_proj, out);
}

// Round 8
// 220.371 us; speedup vs baseline: 1.0018x; 1.0018x over previous
//
#include <hip/hip_runtime.h>

typedef float f32x4 __attribute__((ext_vector_type(4)));
typedef __bf16 bf16x8 __attribute__((ext_vector_type(8)));

static __device__ __forceinline__ unsigned short f2bf(float f) {
    unsigned int u = __builtin_bit_cast(unsigned int, f);
    u += 0x7fffu + ((u >> 16) & 1u);
    return (unsigned short)(u >> 16);
}
static __device__ __forceinline__ unsigned short bfc(float f) {
    return __builtin_bit_cast(unsigned short, (__bf16)f);
}

#define QSC 0.18033688011112042f   // log2(e)/sqrt(HD) folded into Q

typedef const __attribute__((address_space(1))) unsigned int gu32;
typedef __attribute__((address_space(3))) unsigned int lu32;
static __device__ __forceinline__ void gload_lds16(const unsigned short* g, unsigned short* l) {
    __builtin_amdgcn_global_load_lds((gu32*)g, (lu32*)l, 16, 0, 0);
}
#define BAR() asm volatile("s_barrier" ::: "memory")

// ---------------- fp32 -> bf16 elementwise convert ----------------
__global__ __launch_bounds__(256)
void cvt_bf16(const float* __restrict__ in, unsigned short* __restrict__ out) {
    int i = blockIdx.x * 256 + threadIdx.x;
    const float4* p = (const float4*)in + (size_t)i * 2;
    float4 a = p[0], b = p[1];
    union { unsigned short s[8]; uint4 v; } u;
    u.s[0] = f2bf(a.x); u.s[1] = f2bf(a.y); u.s[2] = f2bf(a.z); u.s[3] = f2bf(a.w);
    u.s[4] = f2bf(b.x); u.s[5] = f2bf(b.y); u.s[6] = f2bf(b.z); u.s[7] = f2bf(b.w);
    ((uint4*)out)[i] = u.v;
}

// ---------------- weight transpose+convert: w[K][N] fp32 -> wT[N][K] bf16 ----------------
__global__ __launch_bounds__(256)
void transpose_w(const float* __restrict__ w, unsigned short* __restrict__ wT,
                 int K, int N) {
    __shared__ unsigned short Lt[64][65];
    const int k0 = blockIdx.x * 64, n0 = blockIdx.y * 64;
    const int t = threadIdx.x;
    const int r = t >> 4, c4 = (t & 15) * 4;
    #pragma unroll
    for (int i = 0; i < 4; i++) {
        int rr = r + i * 16;
        float4 v = *(const float4*)(w + (k0 + rr) * N + n0 + c4);
        Lt[rr][c4 + 0] = f2bf(v.x); Lt[rr][c4 + 1] = f2bf(v.y);
        Lt[rr][c4 + 2] = f2bf(v.z); Lt[rr][c4 + 3] = f2bf(v.w);
    }
    __syncthreads();
    const int rn = t >> 3, ks = (t & 7) * 8;
    #pragma unroll
    for (int i = 0; i < 2; i++) {
        int rr = rn + i * 32;
        unsigned short tmp[8];
        #pragma unroll
        for (int j = 0; j < 8; j++) tmp[j] = Lt[ks + j][rr];
        *(uint4*)(wT + (n0 + rr) * K + k0 + ks) = *(const uint4*)tmp;
    }
}

// ---------------- QKV GEMM: 256x256 tile, BK=64, 8-phase counted-vmcnt ----------------
// st_16x32-style swizzle: elem ^= ((row>>2)&1)<<4 on BOTH gload-source and ds_read.
#define GK 1024
#define NT 16   // K / 64

__global__ __launch_bounds__(512, 2)
void qkv_gemm3(const unsigned short* __restrict__ A,
               const unsigned short* __restrict__ Bt,
               const float* __restrict__ bias,
               unsigned short* __restrict__ q_ws,
               unsigned short* __restrict__ k_ws,
               unsigned short* __restrict__ vT_ws)
{
    __shared__ unsigned short L[2][2][16384];   // [dbuf][A/B][256 rows x 64] = 128 KiB
    const int tid = threadIdx.x;
    const int lane = tid & 63, w = tid >> 6;        // 8 waves
    const int l15 = lane & 15, lhi = lane >> 4;
    const int m0 = blockIdx.x * 256, n0 = blockIdx.y * 256;
    const int wr = w >> 2, wc = w & 3;              // wave grid 2M x 4N

    // staging: lane chunk -> row = h*128 + j*64 + w*8 + (lane>>3), col = (lane&7)*8
    // row bit2 = (lane>>5)&1 for all h/j  ->  single swizzled source col per thread
    const int srow0 = w * 8 + (lane >> 3);
    const int selem = ((lane & 7) * 8) ^ (((lane >> 5) & 1) << 4);
    const unsigned short* gA0 = A  + (size_t)(m0 + srow0) * GK + selem;
    const unsigned short* gB0 = Bt + (size_t)(n0 + srow0) * GK + selem;

    #define STAGE(op, h, bufi, kt) do { \
        const unsigned short* _s = ((op) ? gB0 : gA0) + (size_t)(h) * 128 * GK + (kt) * 64; \
        unsigned short* _d = &L[bufi][op][(h) * 8192 + w * 512]; \
        gload_lds16(_s, _d); \
        gload_lds16(_s + 64 * GK, _d + 4096); \
    } while (0)

    // fragment reads: row = base16 + l15  ->  bit2 of row = (l15>>2)&1
    const int vsw = ((l15 >> 2) & 1) << 4;
    const int c0 = (lhi * 8) ^ vsw;
    const int c1 = (32 + lhi * 8) ^ vsw;
    const int arb = (wr * 128 + l15) * 64;
    const int brb = (wc * 64 + l15) * 64;

    f32x4 acc[8][4] = {};

    // prologue: t0 full + t1 B-halves; vmcnt(4) => t0 landed
    STAGE(0, 0, 0, 0); STAGE(0, 1, 0, 0); STAGE(1, 0, 0, 0); STAGE(1, 1, 0, 0);
    STAGE(1, 0, 1, 1); STAGE(1, 1, 1, 1);
    asm volatile("s_waitcnt vmcnt(4)" ::: "memory");
    BAR();

    for (int t = 0; t < NT; ++t) {
        const int buf = t & 1;
        const unsigned short* La = &L[buf][0][0];
        const unsigned short* Lb = &L[buf][1][0];
        bf16x8 aq[4][2], b0q[2][2], b1q[2][2];

        // ---- P1: read A(qm0) + B(qn1) ; stage A0(t+1) -> buf^1
        #pragma unroll
        for (int f = 0; f < 4; ++f) {
            aq[f][0] = *(const bf16x8*)&La[arb + f * 1024 + c0];
            aq[f][1] = *(const bf16x8*)&La[arb + f * 1024 + c1];
        }
        #pragma unroll
        for (int g = 0; g < 2; ++g) {
            b1q[g][0] = *(const bf16x8*)&Lb[brb + (2 + g) * 1024 + c0];
            b1q[g][1] = *(const bf16x8*)&Lb[brb + (2 + g) * 1024 + c1];
        }
        if (t + 1 < NT) STAGE(0, 0, buf ^ 1, t + 1);
        BAR();
        __builtin_amdgcn_s_setprio(1);
        #pragma unroll
        for (int f = 0; f < 4; ++f)
            #pragma unroll
            for (int g = 0; g < 2; ++g) {
                acc[f][2 + g] = __builtin_amdgcn_mfma_f32_16x16x32_bf16(aq[f][0], b1q[g][0], acc[f][2 + g], 0, 0, 0);
                acc[f][2 + g] = __builtin_amdgcn_mfma_f32_16x16x32_bf16(aq[f][1], b1q[g][1], acc[f][2 + g], 0, 0, 0);
            }
        __builtin_amdgcn_s_setprio(0);
        BAR();

        // ---- P2: read B(qn0) ; stage A1(t+1) -> buf^1
        #pragma unroll
        for (int g = 0; g < 2; ++g) {
            b0q[g][0] = *(const bf16x8*)&Lb[brb + g * 1024 + c0];
            b0q[g][1] = *(const bf16x8*)&Lb[brb + g * 1024 + c1];
        }
        if (t + 1 < NT) STAGE(0, 1, buf ^ 1, t + 1);
        BAR();
        __builtin_amdgcn_s_setprio(1);
        #pragma unroll
        for (int f = 0; f < 4; ++f)
            #pragma unroll
            for (int g = 0; g < 2; ++g) {
                acc[f][g] = __builtin_amdgcn_mfma_f32_16x16x32_bf16(aq[f][0], b0q[g][0], acc[f][g], 0, 0, 0);
                acc[f][g] = __builtin_amdgcn_mfma_f32_16x16x32_bf16(aq[f][1], b0q[g][1], acc[f][g], 0, 0, 0);
            }
        __builtin_amdgcn_s_setprio(0);
        BAR();

        // ---- P3: read A(qm1) ; stage B0(t+2) -> buf (B(t) reads done at P2)
        #pragma unroll
        for (int f = 0; f < 4; ++f) {
            aq[f][0] = *(const bf16x8*)&La[arb + (4 + f) * 1024 + c0];
            aq[f][1] = *(const bf16x8*)&La[arb + (4 + f) * 1024 + c1];
        }
        if (t + 2 < NT) STAGE(1, 0, buf, t + 2);
        BAR();
        __builtin_amdgcn_s_setprio(1);
        #pragma unroll
        for (int f = 0; f < 4; ++f)
            #pragma unroll
            for (int g = 0; g < 2; ++g) {
                acc[4 + f][g] = __builtin_amdgcn_mfma_f32_16x16x32_bf16(aq[f][0], b0q[g][0], acc[4 + f][g], 0, 0, 0);
                acc[4 + f][g] = __builtin_amdgcn_mfma_f32_16x16x32_bf16(aq[f][1], b0q[g][1], acc[4 + f][g], 0, 0, 0);
            }
        __builtin_amdgcn_s_setprio(0);
        BAR();

        // ---- P4: stage B1(t+2) -> buf ; counted vmcnt => tile t+1 landed
        if (t + 2 < NT) {
            STAGE(1, 1, buf, t + 2);
            asm volatile("s_waitcnt vmcnt(4)" ::: "memory");
        } else {
            asm volatile("s_waitcnt vmcnt(0)" ::: "memory");
        }
        BAR();
        __builtin_amdgcn_s_setprio(1);
        #pragma unroll
        for (int f = 0; f < 4; ++f)
            #pragma unroll
            for (int g = 0; g < 2; ++g) {
                acc[4 + f][2 + g] = __builtin_amdgcn_mfma_f32_16x16x32_bf16(aq[f][0], b1q[g][0], acc[4 + f][2 + g], 0, 0, 0);
                acc[4 + f][2 + g] = __builtin_amdgcn_mfma_f32_16x16x32_bf16(aq[f][1], b1q[g][1], acc[4 + f][2 + g], 0, 0, 0);
            }
        __builtin_amdgcn_s_setprio(0);
        BAR();
    }
    #undef STAGE

    // epilogue: bias + QKV scatter (Q scaled, V transposed)
    #pragma unroll
    for (int g = 0; g < 4; ++g) {
        int col = n0 + wc * 64 + g * 16 + l15;
        float bv = bias[col];
        int which = col >> 10;          // 0=Q 1=K 2=V
        int d = col & 1023;
        int h = d >> 6, hd = d & 63;
        #pragma unroll
        for (int f = 0; f < 8; ++f) {
            #pragma unroll
            for (int j = 0; j < 4; ++j) {
                int row = m0 + wr * 128 + f * 16 + lhi * 4 + j;
                int b = row >> 11, tt = row & 2047;
                float val = acc[f][g][j] + bv;
                int bh = b * 16 + h;
                if (which == 0)      q_ws[(bh * 2048 + tt) * 64 + hd] = f2bf(val * QSC);
                else if (which == 1) k_ws[(bh * 2048 + tt) * 64 + hd] = f2bf(val);
                else                 vT_ws[(bh * 64 + hd) * 2048 + tt] = f2bf(val);
            }
        }
    }
}

// ---------------- Flash attention (causal) ----------------
#define LKK 72

__global__ __launch_bounds__(512, 4)
void attn_fwd(const unsigned short* __restrict__ q_ws,
              const unsigned short* __restrict__ k_ws,
              const unsigned short* __restrict__ vT_ws,
              unsigned short* __restrict__ attn_ws)
{
    __shared__ unsigned short Kb[2][64 * LKK];
    __shared__ unsigned short Vb[2][64 * LKK];
    __shared__ unsigned short Pl[8][16 * 64];

    const int bh = blockIdx.x;
    const int p  = blockIdx.y;
    const int b = bh >> 4, h = bh & 15;
    const int tid = threadIdx.x;
    const int lane = tid & 63, wid = tid >> 6;
    const int l15 = lane & 15, lhi = lane >> 4;
    const int tbase = bh * 2048;
    const float NINF = -__builtin_inff();

    const int r0 = tid >> 3;
    const int c0 = (tid & 7) * 8;
    const unsigned short* kg = k_ws + (size_t)(tbase + r0) * 64 + c0;
    const unsigned short* vg = vT_ws + ((size_t)bh * 64 + r0) * 2048 + c0;

    unsigned short* Pw = &Pl[wid][0];
    const int xr = l15 & 7;

    #pragma unroll 1
    for (int seg = 0; seg < 2; ++seg) {
        const int qb = seg ? p : 15 - p;
        const int q0 = qb * 128;
        const int qrow = q0 + wid * 16;
        const int nkv = 2 * (qb + 1);

        bf16x8 qf[2];
        #pragma unroll
        for (int ks = 0; ks < 2; ks++)
            qf[ks] = *(const bf16x8*)(q_ws + (size_t)(tbase + qrow + l15) * 64 + ks * 32 + lhi * 8);

        f32x4 o[4] = {};
        float mreg = NINF, lst = 0.f;

        {
            uint4 ka = *(const uint4*)(kg);
            uint4 va = *(const uint4*)(vg);
            *(uint4*)(&Kb[0][r0 * LKK + c0]) = ka;
            *(uint4*)(&Vb[0][r0 * LKK + c0]) = va;
        }
        __syncthreads();

        int cur = 0;
        for (int kb = 0; kb < nkv; ++kb) {
            const int k0 = kb * 64;
            const int knx = (kb + 1 < nkv ? kb + 1 : kb) * 64;
            uint4 ka = *(const uint4*)(kg + (size_t)knx * 64);
            uint4 va = *(const uint4*)(vg + knx);

            if (k0 <= qrow + 15) {
                f32x4 s[4] = {};
                __builtin_amdgcn_s_setprio(1);
                #pragma unroll
                for (int ks = 0; ks < 2; ks++) {
                    bf16x8 kf[4];
                    #pragma unroll
                    for (int n = 0; n < 4; n++)
                        kf[n] = *(const bf16x8*)(&Kb[cur][(n * 16 + l15) * LKK + ks * 32 + lhi * 8]);
                    #pragma unroll
                    for (int n = 0; n < 4; n++)
                        s[n] = __builtin_amdgcn_mfma_f32_16x16x32_bf16(kf[n], qf[ks], s[n], 0, 0, 0);
                }
                __builtin_amdgcn_s_setprio(0);
                if (k0 + 63 > qrow) {
                    int qg = qrow + l15;
                    #pragma unroll
                    for (int n = 0; n < 4; n++) {
                        int kgl = k0 + n * 16 + lhi * 4;
                        #pragma unroll
                        for (int j = 0; j < 4; j++)
                            s[n][j] = (kgl + j <= qg) ? s[n][j] : NINF;
                    }
                }
                float mx = NINF;
                #pragma unroll
                for (int n = 0; n < 4; n++)
                    #pragma unroll
                    for (int j = 0; j < 4; j++)
                        mx = fmaxf(mx, s[n][j]);
                mx = fmaxf(mx, __shfl_xor(mx, 16));
                mx = fmaxf(mx, __shfl_xor(mx, 32));

                if (__all(mx <= mreg + 8.f)) {
                    float rs = 0.f;
                    #pragma unroll
                    for (int n = 0; n < 4; n++)
                        #pragma unroll
                        for (int j = 0; j < 4; j++) {
                            float pv = exp2f(s[n][j] - mreg);
                            s[n][j] = pv;
                            rs += pv;
                        }
                    rs += __shfl_xor(rs, 16);
                    rs += __shfl_xor(rs, 32);
                    lst += rs;
                } else {
                    float mnew = fmaxf(mreg, mx);
                    float al = exp2f(mreg - mnew);
                    mreg = mnew;
                    float rs = 0.f;
                    #pragma unroll
                    for (int n = 0; n < 4; n++)
                        #pragma unroll
                        for (int j = 0; j < 4; j++) {
                            float pv = exp2f(s[n][j] - mnew);
                            s[n][j] = pv;
                            rs += pv;
                        }
                    rs += __shfl_xor(rs, 16);
                    rs += __shfl_xor(rs, 32);
                    lst = lst * al + rs;
                    #pragma unroll
                    for (int j = 0; j < 4; j++) {
                        float a = __shfl(al, lhi * 4 + j);
                        #pragma unroll
                        for (int nd = 0; nd < 4; nd++)
                            o[nd][j] *= a;
                    }
                }
                #pragma unroll
                for (int n = 0; n < 4; n++) {
                    ushort4 pk;
                    pk.x = bfc(s[n][0]); pk.y = bfc(s[n][1]);
                    pk.z = bfc(s[n][2]); pk.w = bfc(s[n][3]);
                    int chunk = (2 * n + (lhi >> 1)) ^ xr;
                    *(ushort4*)(&Pw[l15 * 64 + chunk * 8 + (lhi & 1) * 4]) = pk;
                }
                __builtin_amdgcn_s_setprio(1);
                #pragma unroll
                for (int ks = 0; ks < 2; ks++) {
                    int chunk = (4 * ks + lhi) ^ xr;
                    bf16x8 pf = *(const bf16x8*)(&Pw[l15 * 64 + chunk * 8]);
                    bf16x8 vf[4];
                    #pragma unroll
                    for (int nd = 0; nd < 4; nd++)
                        vf[nd] = *(const bf16x8*)(&Vb[cur][(nd * 16 + l15) * LKK + ks * 32 + lhi * 8]);
                    #pragma unroll
                    for (int nd = 0; nd < 4; nd++)
                        o[nd] = __builtin_amdgcn_mfma_f32_16x16x32_bf16(pf, vf[nd], o[nd], 0, 0, 0);
                }
                __builtin_amdgcn_s_setprio(0);
            }
            *(uint4*)(&Kb[cur ^ 1][r0 * LKK + c0]) = ka;
            *(uint4*)(&Vb[cur ^ 1][r0 * LKK + c0]) = va;
            __syncthreads();
            cur ^= 1;
        }
        #pragma unroll
        for (int j = 0; j < 4; j++) {
            float lv = __shfl(lst, lhi * 4 + j);
            float inv = 1.0f / lv;
            int t = qrow + lhi * 4 + j;
            #pragma unroll
            for (int nd = 0; nd < 4; nd++) {
                int d = nd * 16 + l15;
                attn_ws[((size_t)(b * 2048 + t) * 16 + h) * 64 + d] = f2bf(o[nd][j] * inv);
            }
        }
    }
}

// ---------------- Output projection GEMM (2-phase prefetch pipeline) ----------------
__global__ __launch_bounds__(256)
void proj_gemm2(const unsigned short* __restrict__ A,
                const unsigned short* __restrict__ Bt,
                const float* __restrict__ bias, float* __restrict__ out)
{
    const int K = 1024, N = 1024;
    __shared__ unsigned short Al[2][128 * 32];
    __shared__ unsigned short Bl[2][128 * 32];
    const int tid = threadIdx.x;
    const int lane = tid & 63, w = tid >> 6;
    const int l15 = lane & 15, lhi = lane >> 4;
    const int m0 = blockIdx.x * 128, n0 = blockIdx.y * 128;
    const int wm = (w >> 1) * 64, wn = (w & 1) * 64;

    const int srow = w * 32 + (lane >> 2);
    const int sslot = lane & 3;
    const unsigned short* ga = A + (size_t)(m0 + srow) * K + sslot * 8;
    const unsigned short* gb = Bt + (size_t)(n0 + srow) * K + sslot * 8;
    const int lofs = w * 32 * 32;

    f32x4 acc[4][4] = {};

    gload_lds16(ga, &Al[0][lofs]);
    gload_lds16(ga + 16 * K, &Al[0][lofs + 512]);
    gload_lds16(gb, &Bl[0][lofs]);
    gload_lds16(gb + 16 * K, &Bl[0][lofs + 512]);
    __syncthreads();

    int cur = 0;
    for (int k0 = 0; k0 < K; k0 += 32) {
        const int nxt = cur ^ 1;
        if (k0 + 32 < K) {
            gload_lds16(ga + k0 + 32,          &Al[nxt][lofs]);
            gload_lds16(ga + k0 + 32 + 16 * K, &Al[nxt][lofs + 512]);
            gload_lds16(gb + k0 + 32,          &Bl[nxt][lofs]);
            gload_lds16(gb + k0 + 32 + 16 * K, &Bl[nxt][lofs + 512]);
        }
        bf16x8 af[4], bfr[4];
        #pragma unroll
        for (int m = 0; m < 4; m++)
            af[m] = *(const bf16x8*)(&Al[cur][(wm + m * 16 + l15) * 32 + lhi * 8]);
        #pragma unroll
        for (int n = 0; n < 4; n++)
            bfr[n] = *(const bf16x8*)(&Bl[cur][(wn + n * 16 + l15) * 32 + lhi * 8]);
        __builtin_amdgcn_s_setprio(1);
        #pragma unroll
        for (int m = 0; m < 4; m++)
            #pragma unroll
            for (int n = 0; n < 4; n++)
                acc[m][n] = __builtin_amdgcn_mfma_f32_16x16x32_bf16(af[m], bfr[n], acc[m][n], 0, 0, 0);
        __builtin_amdgcn_s_setprio(0);
        __syncthreads();
        cur = nxt;
    }

    #pragma unroll
    for (int n = 0; n < 4; n++) {
        int col = n0 + wn + n * 16 + l15;
        float bv = bias[col];
        #pragma unroll
        for (int m = 0; m < 4; m++)
            #pragma unroll
            for (int j = 0; j < 4; j++) {
                int row = m0 + wm + m * 16 + lhi * 4 + j;
                out[row * N + col] = acc[m][n][j] + bv;
            }
    }
}

extern "C" void kernel_launch(void* const* d_in, const int* in_sizes, int n_in,
                              void* d_out, int out_size, void* d_ws, size_t ws_size,
                              hipStream_t stream)
{
    const float* x      = (const float*)d_in[0];
    const float* w_qkv  = (const float*)d_in[1];
    const float* b_qkv  = (const float*)d_in[2];
    const float* w_proj = (const float*)d_in[3];
    const float* b_proj = (const float*)d_in[4];
    float* out = (float*)d_out;

    const size_t SEG = (size_t)8 * 1024 * 1024;
    unsigned short* q_ws    = (unsigned short*)d_ws;
    unsigned short* k_ws    = q_ws + SEG;
    unsigned short* vT_ws   = k_ws + SEG;
    unsigned short* attn_ws = vT_ws + SEG;

    unsigned short* x_bf   = (unsigned short*)d_out;          // d_out as scratch
    unsigned short* wqkvT  = x_bf + SEG;
    unsigned short* wprojT = q_ws;                            // dead after attn

    cvt_bf16<<<4096, 256, 0, stream>>>(x, x_bf);
    transpose_w<<<dim3(16, 48), 256, 0, stream>>>(w_qkv, wqkvT, 1024, 3072);
    qkv_gemm3<<<dim3(32, 12), 512, 0, stream>>>(x_bf, wqkvT, b_qkv, q_ws, k_ws, vT_ws);
    attn_fwd<<<dim3(64, 8), 512, 0, stream>>>(q_ws, k_ws, vT_ws, attn_ws);
    transpose_w<<<dim3(16, 16), 256, 0, stream>>>(w_proj, wprojT, 1024, 1024);
    proj_gemm2<<<dim3(64, 8), 256, 0, stream>>>(attn_ws, wprojT, b_proj, out);
}

// Round 9
// 219.054 us; speedup vs baseline: 1.0079x; 1.0060x over previous
//
#include <hip/hip_runtime.h>

typedef float f32x4 __attribute__((ext_vector_type(4)));
typedef __bf16 bf16x8 __attribute__((ext_vector_type(8)));

static __device__ __forceinline__ unsigned short f2bf(float f) {
    unsigned int u = __builtin_bit_cast(unsigned int, f);
    u += 0x7fffu + ((u >> 16) & 1u);
    return (unsigned short)(u >> 16);
}
static __device__ __forceinline__ unsigned short bfc(float f) {
    return __builtin_bit_cast(unsigned short, (__bf16)f);
}

#define QSC 0.18033688011112042f   // log2(e)/sqrt(HD) folded into Q

typedef const __attribute__((address_space(1))) unsigned int gu32;
typedef __attribute__((address_space(3))) unsigned int lu32;
static __device__ __forceinline__ void gload_lds16(const unsigned short* g, unsigned short* l) {
    __builtin_amdgcn_global_load_lds((gu32*)g, (lu32*)l, 16, 0, 0);
}
#define BAR() asm volatile("s_barrier" ::: "memory")

// ---------------- fp32 -> bf16 elementwise convert ----------------
__global__ __launch_bounds__(256)
void cvt_bf16(const float* __restrict__ in, unsigned short* __restrict__ out) {
    int i = blockIdx.x * 256 + threadIdx.x;
    const float4* p = (const float4*)in + (size_t)i * 2;
    float4 a = p[0], b = p[1];
    union { unsigned short s[8]; uint4 v; } u;
    u.s[0] = f2bf(a.x); u.s[1] = f2bf(a.y); u.s[2] = f2bf(a.z); u.s[3] = f2bf(a.w);
    u.s[4] = f2bf(b.x); u.s[5] = f2bf(b.y); u.s[6] = f2bf(b.z); u.s[7] = f2bf(b.w);
    ((uint4*)out)[i] = u.v;
}

// ---------------- weight transpose+convert: w[K][N] fp32 -> wT[N][K] bf16 ----------------
__global__ __launch_bounds__(256)
void transpose_w(const float* __restrict__ w, unsigned short* __restrict__ wT,
                 int K, int N) {
    __shared__ unsigned short Lt[64][65];
    const int k0 = blockIdx.x * 64, n0 = blockIdx.y * 64;
    const int t = threadIdx.x;
    const int r = t >> 4, c4 = (t & 15) * 4;
    #pragma unroll
    for (int i = 0; i < 4; i++) {
        int rr = r + i * 16;
        float4 v = *(const float4*)(w + (k0 + rr) * N + n0 + c4);
        Lt[rr][c4 + 0] = f2bf(v.x); Lt[rr][c4 + 1] = f2bf(v.y);
        Lt[rr][c4 + 2] = f2bf(v.z); Lt[rr][c4 + 3] = f2bf(v.w);
    }
    __syncthreads();
    const int rn = t >> 3, ks = (t & 7) * 8;
    #pragma unroll
    for (int i = 0; i < 2; i++) {
        int rr = rn + i * 32;
        unsigned short tmp[8];
        #pragma unroll
        for (int j = 0; j < 8; j++) tmp[j] = Lt[ks + j][rr];
        *(uint4*)(wT + (n0 + rr) * K + k0 + ks) = *(const uint4*)tmp;
    }
}

// ---------------- QKV GEMM: 256x256, BK=64, 8-phase ----------------
// 3-bit granule swizzle slot = g ^ (row&7): every ds_read_b128 spans all 32 banks.
// All 4 stages of tile t+2 issued at P3/P4 -> vmcnt(8) waits only on >=5-phase-old loads.
#define GK 1024
#define NT 16   // K / 64

__global__ __launch_bounds__(512, 2)
void qkv_gemm3(const unsigned short* __restrict__ A,
               const unsigned short* __restrict__ Bt,
               const float* __restrict__ bias,
               unsigned short* __restrict__ q_ws,
               unsigned short* __restrict__ k_ws,
               unsigned short* __restrict__ vT_ws)
{
    __shared__ unsigned short L[2][2][16384];   // [dbuf][A/B][256 x 64] = 128 KiB
    const int tid = threadIdx.x;
    const int lane = tid & 63, w = tid >> 6;        // 8 waves
    const int l15 = lane & 15, lhi = lane >> 4;
    const int m0 = blockIdx.x * 256, n0 = blockIdx.y * 256;
    const int wr = w >> 2, wc = w & 3;              // wave grid 2M x 4N

    // staging: row = h*128 + j*64 + w*8 + (lane>>3); LDS slot granule = lane&7
    // slot holds global granule g = (lane&7) ^ (row&7), row&7 = (lane>>3)&7
    const int srow0 = w * 8 + (lane >> 3);
    const int selem = (((lane & 7) ^ ((lane >> 3) & 7)) * 8);
    const unsigned short* gA0 = A  + (size_t)(m0 + srow0) * GK + selem;
    const unsigned short* gB0 = Bt + (size_t)(n0 + srow0) * GK + selem;

    #define STAGE(op, h, bufi, kt) do { \
        const unsigned short* _s = ((op) ? gB0 : gA0) + (size_t)(h) * 128 * GK + (kt) * 64; \
        unsigned short* _d = &L[bufi][op][(h) * 8192 + w * 512]; \
        gload_lds16(_s, _d); \
        gload_lds16(_s + 64 * GK, _d + 4096); \
    } while (0)

    // fragment reads: row&7 = l15&7; granule g = ks*4+lhi -> slot = g ^ (l15&7)
    const int c0 = ((lhi ^ (l15 & 7)) * 8);
    const int c1 = c0 ^ 32;
    const int arb = (wr * 128 + l15) * 64;
    const int brb = (wc * 64 + l15) * 64;

    f32x4 acc[8][4] = {};

    // prologue: stage t0 + t1 fully; vmcnt(8) => t0 landed
    STAGE(0, 0, 0, 0); STAGE(0, 1, 0, 0); STAGE(1, 0, 0, 0); STAGE(1, 1, 0, 0);
    STAGE(0, 0, 1, 1); STAGE(0, 1, 1, 1); STAGE(1, 0, 1, 1); STAGE(1, 1, 1, 1);
    asm volatile("s_waitcnt vmcnt(8)" ::: "memory");
    BAR();

    for (int t = 0; t < NT; ++t) {
        const int buf = t & 1;
        const unsigned short* La = &L[buf][0][0];
        const unsigned short* Lb = &L[buf][1][0];
        bf16x8 aq[4][2], b0q[2][2], b1q[2][2];

        // ---- P1: read A(qm0) + B(qn1)
        #pragma unroll
        for (int f = 0; f < 4; ++f) {
            aq[f][0] = *(const bf16x8*)&La[arb + f * 1024 + c0];
            aq[f][1] = *(const bf16x8*)&La[arb + f * 1024 + c1];
        }
        #pragma unroll
        for (int g = 0; g < 2; ++g) {
            b1q[g][0] = *(const bf16x8*)&Lb[brb + (2 + g) * 1024 + c0];
            b1q[g][1] = *(const bf16x8*)&Lb[brb + (2 + g) * 1024 + c1];
        }
        BAR();
        __builtin_amdgcn_s_setprio(1);
        #pragma unroll
        for (int f = 0; f < 4; ++f)
            #pragma unroll
            for (int g = 0; g < 2; ++g) {
                acc[f][2 + g] = __builtin_amdgcn_mfma_f32_16x16x32_bf16(aq[f][0], b1q[g][0], acc[f][2 + g], 0, 0, 0);
                acc[f][2 + g] = __builtin_amdgcn_mfma_f32_16x16x32_bf16(aq[f][1], b1q[g][1], acc[f][2 + g], 0, 0, 0);
            }
        __builtin_amdgcn_s_setprio(0);
        BAR();

        // ---- P2: read B(qn0)
        #pragma unroll
        for (int g = 0; g < 2; ++g) {
            b0q[g][0] = *(const bf16x8*)&Lb[brb + g * 1024 + c0];
            b0q[g][1] = *(const bf16x8*)&Lb[brb + g * 1024 + c1];
        }
        BAR();
        __builtin_amdgcn_s_setprio(1);
        #pragma unroll
        for (int f = 0; f < 4; ++f)
            #pragma unroll
            for (int g = 0; g < 2; ++g) {
                acc[f][g] = __builtin_amdgcn_mfma_f32_16x16x32_bf16(aq[f][0], b0q[g][0], acc[f][g], 0, 0, 0);
                acc[f][g] = __builtin_amdgcn_mfma_f32_16x16x32_bf16(aq[f][1], b0q[g][1], acc[f][g], 0, 0, 0);
            }
        __builtin_amdgcn_s_setprio(0);
        BAR();

        // ---- P3: read A(qm1) ; stage B0(t+2), B1(t+2) -> buf (B(t) fully read at P2)
        #pragma unroll
        for (int f = 0; f < 4; ++f) {
            aq[f][0] = *(const bf16x8*)&La[arb + (4 + f) * 1024 + c0];
            aq[f][1] = *(const bf16x8*)&La[arb + (4 + f) * 1024 + c1];
        }
        if (t + 2 < NT) { STAGE(1, 0, buf, t + 2); STAGE(1, 1, buf, t + 2); }
        BAR();
        __builtin_amdgcn_s_setprio(1);
        #pragma unroll
        for (int f = 0; f < 4; ++f)
            #pragma unroll
            for (int g = 0; g < 2; ++g) {
                acc[4 + f][g] = __builtin_amdgcn_mfma_f32_16x16x32_bf16(aq[f][0], b0q[g][0], acc[4 + f][g], 0, 0, 0);
                acc[4 + f][g] = __builtin_amdgcn_mfma_f32_16x16x32_bf16(aq[f][1], b0q[g][1], acc[4 + f][g], 0, 0, 0);
            }
        __builtin_amdgcn_s_setprio(0);
        BAR();

        // ---- P4: stage A0(t+2), A1(t+2) -> buf (A(t) fully read at P3) ; counted wait
        if (t + 2 < NT) {
            STAGE(0, 0, buf, t + 2); STAGE(0, 1, buf, t + 2);
            asm volatile("s_waitcnt vmcnt(8)" ::: "memory");   // tile t+1 landed
        } else {
            asm volatile("s_waitcnt vmcnt(0)" ::: "memory");
        }
        BAR();
        __builtin_amdgcn_s_setprio(1);
        #pragma unroll
        for (int f = 0; f < 4; ++f)
            #pragma unroll
            for (int g = 0; g < 2; ++g) {
                acc[4 + f][2 + g] = __builtin_amdgcn_mfma_f32_16x16x32_bf16(aq[f][0], b1q[g][0], acc[4 + f][2 + g], 0, 0, 0);
                acc[4 + f][2 + g] = __builtin_amdgcn_mfma_f32_16x16x32_bf16(aq[f][1], b1q[g][1], acc[4 + f][2 + g], 0, 0, 0);
            }
        __builtin_amdgcn_s_setprio(0);
        BAR();
    }
    #undef STAGE

    // epilogue: bias + QKV scatter (Q scaled, V transposed)
    #pragma unroll
    for (int g = 0; g < 4; ++g) {
        int col = n0 + wc * 64 + g * 16 + l15;
        float bv = bias[col];
        int which = col >> 10;          // 0=Q 1=K 2=V
        int d = col & 1023;
        int h = d >> 6, hd = d & 63;
        #pragma unroll
        for (int f = 0; f < 8; ++f) {
            #pragma unroll
            for (int j = 0; j < 4; ++j) {
                int row = m0 + wr * 128 + f * 16 + lhi * 4 + j;
                int b = row >> 11, tt = row & 2047;
                float val = acc[f][g][j] + bv;
                int bh = b * 16 + h;
                if (which == 0)      q_ws[(bh * 2048 + tt) * 64 + hd] = f2bf(val * QSC);
                else if (which == 1) k_ws[(bh * 2048 + tt) * 64 + hd] = f2bf(val);
                else                 vT_ws[(bh * 64 + hd) * 2048 + tt] = f2bf(val);
            }
        }
    }
}

// ---------------- Flash attention (causal) ----------------
#define LKK 72

__global__ __launch_bounds__(512, 4)
void attn_fwd(const unsigned short* __restrict__ q_ws,
              const unsigned short* __restrict__ k_ws,
              const unsigned short* __restrict__ vT_ws,
              unsigned short* __restrict__ attn_ws)
{
    __shared__ unsigned short Kb[2][64 * LKK];
    __shared__ unsigned short Vb[2][64 * LKK];
    __shared__ unsigned short Pl[8][16 * 64];

    const int bh = blockIdx.x;
    const int p  = blockIdx.y;
    const int b = bh >> 4, h = bh & 15;
    const int tid = threadIdx.x;
    const int lane = tid & 63, wid = tid >> 6;
    const int l15 = lane & 15, lhi = lane >> 4;
    const int tbase = bh * 2048;
    const float NINF = -__builtin_inff();

    const int r0 = tid >> 3;
    const int c0 = (tid & 7) * 8;
    const unsigned short* kg = k_ws + (size_t)(tbase + r0) * 64 + c0;
    const unsigned short* vg = vT_ws + ((size_t)bh * 64 + r0) * 2048 + c0;

    unsigned short* Pw = &Pl[wid][0];
    const int xr = l15 & 7;

    #pragma unroll 1
    for (int seg = 0; seg < 2; ++seg) {
        const int qb = seg ? p : 15 - p;
        const int q0 = qb * 128;
        const int qrow = q0 + wid * 16;
        const int nkv = 2 * (qb + 1);

        bf16x8 qf[2];
        #pragma unroll
        for (int ks = 0; ks < 2; ks++)
            qf[ks] = *(const bf16x8*)(q_ws + (size_t)(tbase + qrow + l15) * 64 + ks * 32 + lhi * 8);

        f32x4 o[4] = {};
        float mreg = NINF, lst = 0.f;

        {
            uint4 ka = *(const uint4*)(kg);
            uint4 va = *(const uint4*)(vg);
            *(uint4*)(&Kb[0][r0 * LKK + c0]) = ka;
            *(uint4*)(&Vb[0][r0 * LKK + c0]) = va;
        }
        __syncthreads();

        int cur = 0;
        for (int kb = 0; kb < nkv; ++kb) {
            const int k0 = kb * 64;
            const int knx = (kb + 1 < nkv ? kb + 1 : kb) * 64;
            uint4 ka = *(const uint4*)(kg + (size_t)knx * 64);
            uint4 va = *(const uint4*)(vg + knx);

            if (k0 <= qrow + 15) {
                f32x4 s[4] = {};
                __builtin_amdgcn_s_setprio(1);
                #pragma unroll
                for (int ks = 0; ks < 2; ks++) {
                    bf16x8 kf[4];
                    #pragma unroll
                    for (int n = 0; n < 4; n++)
                        kf[n] = *(const bf16x8*)(&Kb[cur][(n * 16 + l15) * LKK + ks * 32 + lhi * 8]);
                    #pragma unroll
                    for (int n = 0; n < 4; n++)
                        s[n] = __builtin_amdgcn_mfma_f32_16x16x32_bf16(kf[n], qf[ks], s[n], 0, 0, 0);
                }
                __builtin_amdgcn_s_setprio(0);
                if (k0 + 63 > qrow) {
                    int qg = qrow + l15;
                    #pragma unroll
                    for (int n = 0; n < 4; n++) {
                        int kgl = k0 + n * 16 + lhi * 4;
                        #pragma unroll
                        for (int j = 0; j < 4; j++)
                            s[n][j] = (kgl + j <= qg) ? s[n][j] : NINF;
                    }
                }
                float mx = NINF;
                #pragma unroll
                for (int n = 0; n < 4; n++)
                    #pragma unroll
                    for (int j = 0; j < 4; j++)
                        mx = fmaxf(mx, s[n][j]);
                mx = fmaxf(mx, __shfl_xor(mx, 16));
                mx = fmaxf(mx, __shfl_xor(mx, 32));

                if (__all(mx <= mreg + 8.f)) {
                    float rs = 0.f;
                    #pragma unroll
                    for (int n = 0; n < 4; n++)
                        #pragma unroll
                        for (int j = 0; j < 4; j++) {
                            float pv = exp2f(s[n][j] - mreg);
                            s[n][j] = pv;
                            rs += pv;
                        }
                    rs += __shfl_xor(rs, 16);
                    rs += __shfl_xor(rs, 32);
                    lst += rs;
                } else {
                    float mnew = fmaxf(mreg, mx);
                    float al = exp2f(mreg - mnew);
                    mreg = mnew;
                    float rs = 0.f;
                    #pragma unroll
                    for (int n = 0; n < 4; n++)
                        #pragma unroll
                        for (int j = 0; j < 4; j++) {
                            float pv = exp2f(s[n][j] - mnew);
                            s[n][j] = pv;
                            rs += pv;
                        }
                    rs += __shfl_xor(rs, 16);
                    rs += __shfl_xor(rs, 32);
                    lst = lst * al + rs;
                    #pragma unroll
                    for (int j = 0; j < 4; j++) {
                        float a = __shfl(al, lhi * 4 + j);
                        #pragma unroll
                        for (int nd = 0; nd < 4; nd++)
                            o[nd][j] *= a;
                    }
                }
                #pragma unroll
                for (int n = 0; n < 4; n++) {
                    ushort4 pk;
                    pk.x = bfc(s[n][0]); pk.y = bfc(s[n][1]);
                    pk.z = bfc(s[n][2]); pk.w = bfc(s[n][3]);
                    int chunk = (2 * n + (lhi >> 1)) ^ xr;
                    *(ushort4*)(&Pw[l15 * 64 + chunk * 8 + (lhi & 1) * 4]) = pk;
                }
                __builtin_amdgcn_s_setprio(1);
                #pragma unroll
                for (int ks = 0; ks < 2; ks++) {
                    int chunk = (4 * ks + lhi) ^ xr;
                    bf16x8 pf = *(const bf16x8*)(&Pw[l15 * 64 + chunk * 8]);
                    bf16x8 vf[4];
                    #pragma unroll
                    for (int nd = 0; nd < 4; nd++)
                        vf[nd] = *(const bf16x8*)(&Vb[cur][(nd * 16 + l15) * LKK + ks * 32 + lhi * 8]);
                    #pragma unroll
                    for (int nd = 0; nd < 4; nd++)
                        o[nd] = __builtin_amdgcn_mfma_f32_16x16x32_bf16(pf, vf[nd], o[nd], 0, 0, 0);
                }
                __builtin_amdgcn_s_setprio(0);
            }
            *(uint4*)(&Kb[cur ^ 1][r0 * LKK + c0]) = ka;
            *(uint4*)(&Vb[cur ^ 1][r0 * LKK + c0]) = va;
            __syncthreads();
            cur ^= 1;
        }
        #pragma unroll
        for (int j = 0; j < 4; j++) {
            float lv = __shfl(lst, lhi * 4 + j);
            float inv = 1.0f / lv;
            int t = qrow + lhi * 4 + j;
            #pragma unroll
            for (int nd = 0; nd < 4; nd++) {
                int d = nd * 16 + l15;
                attn_ws[((size_t)(b * 2048 + t) * 16 + h) * 64 + d] = f2bf(o[nd][j] * inv);
            }
        }
    }
}

// ---------------- Output projection GEMM (2-phase prefetch pipeline) ----------------
__global__ __launch_bounds__(256)
void proj_gemm2(const unsigned short* __restrict__ A,
                const unsigned short* __restrict__ Bt,
                const float* __restrict__ bias, float* __restrict__ out)
{
    const int K = 1024, N = 1024;
    __shared__ unsigned short Al[2][128 * 32];
    __shared__ unsigned short Bl[2][128 * 32];
    const int tid = threadIdx.x;
    const int lane = tid & 63, w = tid >> 6;
    const int l15 = lane & 15, lhi = lane >> 4;
    const int m0 = blockIdx.x * 128, n0 = blockIdx.y * 128;
    const int wm = (w >> 1) * 64, wn = (w & 1) * 64;

    const int srow = w * 32 + (lane >> 2);
    const int sslot = lane & 3;
    const unsigned short* ga = A + (size_t)(m0 + srow) * K + sslot * 8;
    const unsigned short* gb = Bt + (size_t)(n0 + srow) * K + sslot * 8;
    const int lofs = w * 32 * 32;

    f32x4 acc[4][4] = {};

    gload_lds16(ga, &Al[0][lofs]);
    gload_lds16(ga + 16 * K, &Al[0][lofs + 512]);
    gload_lds16(gb, &Bl[0][lofs]);
    gload_lds16(gb + 16 * K, &Bl[0][lofs + 512]);
    __syncthreads();

    int cur = 0;
    for (int k0 = 0; k0 < K; k0 += 32) {
        const int nxt = cur ^ 1;
        if (k0 + 32 < K) {
            gload_lds16(ga + k0 + 32,          &Al[nxt][lofs]);
            gload_lds16(ga + k0 + 32 + 16 * K, &Al[nxt][lofs + 512]);
            gload_lds16(gb + k0 + 32,          &Bl[nxt][lofs]);
            gload_lds16(gb + k0 + 32 + 16 * K, &Bl[nxt][lofs + 512]);
        }
        bf16x8 af[4], bfr[4];
        #pragma unroll
        for (int m = 0; m < 4; m++)
            af[m] = *(const bf16x8*)(&Al[cur][(wm + m * 16 + l15) * 32 + lhi * 8]);
        #pragma unroll
        for (int n = 0; n < 4; n++)
            bfr[n] = *(const bf16x8*)(&Bl[cur][(wn + n * 16 + l15) * 32 + lhi * 8]);
        __builtin_amdgcn_s_setprio(1);
        #pragma unroll
        for (int m = 0; m < 4; m++)
            #pragma unroll
            for (int n = 0; n < 4; n++)
                acc[m][n] = __builtin_amdgcn_mfma_f32_16x16x32_bf16(af[m], bfr[n], acc[m][n], 0, 0, 0);
        __builtin_amdgcn_s_setprio(0);
        __syncthreads();
        cur = nxt;
    }

    #pragma unroll
    for (int n = 0; n < 4; n++) {
        int col = n0 + wn + n * 16 + l15;
        float bv = bias[col];
        #pragma unroll
        for (int m = 0; m < 4; m++)
            #pragma unroll
            for (int j = 0; j < 4; j++) {
                int row = m0 + wm + m * 16 + lhi * 4 + j;
                out[row * N + col] = acc[m][n][j] + bv;
            }
    }
}

extern "C" void kernel_launch(void* const* d_in, const int* in_sizes, int n_in,
                              void* d_out, int out_size, void* d_ws, size_t ws_size,
                              hipStream_t stream)
{
    const float* x      = (const float*)d_in[0];
    const float* w_qkv  = (const float*)d_in[1];
    const float* b_qkv  = (const float*)d_in[2];
    const float* w_proj = (const float*)d_in[3];
    const float* b_proj = (const float*)d_in[4];
    float* out = (float*)d_out;

    const size_t SEG = (size_t)8 * 1024 * 1024;
    unsigned short* q_ws    = (unsigned short*)d_ws;
    unsigned short* k_ws    = q_ws + SEG;
    unsigned short* vT_ws   = k_ws + SEG;
    unsigned short* attn_ws = vT_ws + SEG;

    unsigned short* x_bf   = (unsigned short*)d_out;          // d_out as scratch
    unsigned short* wqkvT  = x_bf + SEG;
    unsigned short* wprojT = q_ws;                            // dead after attn

    cvt_bf16<<<4096, 256, 0, stream>>>(x, x_bf);
    transpose_w<<<dim3(16, 48), 256, 0, stream>>>(w_qkv, wqkvT, 1024, 3072);
    qkv_gemm3<<<dim3(32, 12), 512, 0, stream>>>(x_bf, wqkvT, b_qkv, q_ws, k_ws, vT_ws);
    attn_fwd<<<dim3(64, 8), 512, 0, stream>>>(q_ws, k_ws, vT_ws, attn_ws);
    transpose_w<<<dim3(16, 16), 256, 0, stream>>>(w_proj, wprojT, 1024, 1024);
    proj_gemm2<<<dim3(64, 8), 256, 0, stream>>>(attn_ws, wprojT, b_proj, out);
}

// Round 10
// 199.119 us; speedup vs baseline: 1.1088x; 1.1001x over previous
//
#include <hip/hip_runtime.h>

typedef float f32x4 __attribute__((ext_vector_type(4)));
typedef __bf16 bf16x8 __attribute__((ext_vector_type(8)));

static __device__ __forceinline__ unsigned short f2bf(float f) {
    unsigned int u = __builtin_bit_cast(unsigned int, f);
    u += 0x7fffu + ((u >> 16) & 1u);
    return (unsigned short)(u >> 16);
}
static __device__ __forceinline__ unsigned short bfc(float f) {
    return __builtin_bit_cast(unsigned short, (__bf16)f);
}

#define QSC 0.18033688011112042f   // log2(e)/sqrt(HD) folded into Q

typedef const __attribute__((address_space(1))) unsigned int gu32;
typedef __attribute__((address_space(3))) unsigned int lu32;
static __device__ __forceinline__ void gload_lds16(const unsigned short* g, unsigned short* l) {
    __builtin_amdgcn_global_load_lds((gu32*)g, (lu32*)l, 16, 0, 0);
}

// ---------------- fp32 -> bf16 elementwise convert ----------------
__global__ __launch_bounds__(256)
void cvt_bf16(const float* __restrict__ in, unsigned short* __restrict__ out) {
    int i = blockIdx.x * 256 + threadIdx.x;
    const float4* p = (const float4*)in + (size_t)i * 2;
    float4 a = p[0], b = p[1];
    union { unsigned short s[8]; uint4 v; } u;
    u.s[0] = f2bf(a.x); u.s[1] = f2bf(a.y); u.s[2] = f2bf(a.z); u.s[3] = f2bf(a.w);
    u.s[4] = f2bf(b.x); u.s[5] = f2bf(b.y); u.s[6] = f2bf(b.z); u.s[7] = f2bf(b.w);
    ((uint4*)out)[i] = u.v;
}

// ---------------- weight transpose+convert: w[K][N] fp32 -> wT[N][K] bf16 ----------------
__global__ __launch_bounds__(256)
void transpose_w(const float* __restrict__ w, unsigned short* __restrict__ wT,
                 int K, int N) {
    __shared__ unsigned short Lt[64][65];
    const int k0 = blockIdx.x * 64, n0 = blockIdx.y * 64;
    const int t = threadIdx.x;
    const int r = t >> 4, c4 = (t & 15) * 4;
    #pragma unroll
    for (int i = 0; i < 4; i++) {
        int rr = r + i * 16;
        float4 v = *(const float4*)(w + (k0 + rr) * N + n0 + c4);
        Lt[rr][c4 + 0] = f2bf(v.x); Lt[rr][c4 + 1] = f2bf(v.y);
        Lt[rr][c4 + 2] = f2bf(v.z); Lt[rr][c4 + 3] = f2bf(v.w);
    }
    __syncthreads();
    const int rn = t >> 3, ks = (t & 7) * 8;
    #pragma unroll
    for (int i = 0; i < 2; i++) {
        int rr = rn + i * 32;
        unsigned short tmp[8];
        #pragma unroll
        for (int j = 0; j < 8; j++) tmp[j] = Lt[ks + j][rr];
        *(uint4*)(wT + (n0 + rr) * K + k0 + ks) = *(const uint4*)tmp;
    }
}

// ---------------- QKV GEMM (2-phase prefetch + granule swizzle) ----------------
// LDS rows = 64B = 4 granules; conflict-free key: granule ^= (row>>1)&3
// (b128 reads process 16 lanes/phase; key must vary with l15, validated r9)
__global__ __launch_bounds__(256)
void qkv_gemm2(const unsigned short* __restrict__ A,
               const unsigned short* __restrict__ Bt,
               const float* __restrict__ bias,
               unsigned short* __restrict__ q_ws,
               unsigned short* __restrict__ k_ws,
               unsigned short* __restrict__ vT_ws)
{
    const int K = 1024;
    __shared__ unsigned short Al[2][128 * 32];
    __shared__ unsigned short Bl[2][128 * 32];
    const int tid = threadIdx.x;
    const int lane = tid & 63, w = tid >> 6;
    const int l15 = lane & 15, lhi = lane >> 4;
    const int m0 = blockIdx.x * 128, n0 = blockIdx.y * 128;
    const int wm = (w >> 1) * 64, wn = (w & 1) * 64;

    // staging: row = w*32 + c*16 + (lane>>2), LDS granule = lane&3 (linear dest)
    // source granule = (lane&3) ^ ((row>>1)&3) = (lane&3) ^ ((lane>>3)&3)
    const int srow = w * 32 + (lane >> 2);
    const int sg = ((lane & 3) ^ ((lane >> 3) & 3)) * 8;
    const unsigned short* ga = A + (size_t)(m0 + srow) * K + sg;
    const unsigned short* gb = Bt + (size_t)(n0 + srow) * K + sg;
    const int lofs = w * 32 * 32;

    // read: row = base16 + l15 -> key = (l15>>1)&3 ; granule = lhi ^ key
    const int rc = (lhi ^ ((l15 >> 1) & 3)) * 8;

    f32x4 acc[4][4] = {};

    // prologue: stage tile 0 into buffer 0
    gload_lds16(ga, &Al[0][lofs]);
    gload_lds16(ga + 16 * K, &Al[0][lofs + 512]);
    gload_lds16(gb, &Bl[0][lofs]);
    gload_lds16(gb + 16 * K, &Bl[0][lofs + 512]);
    __syncthreads();

    int cur = 0;
    for (int k0 = 0; k0 < K; k0 += 32) {
        const int nxt = cur ^ 1;
        if (k0 + 32 < K) {   // issue next-tile loads BEFORE compute (overlap)
            gload_lds16(ga + k0 + 32,          &Al[nxt][lofs]);
            gload_lds16(ga + k0 + 32 + 16 * K, &Al[nxt][lofs + 512]);
            gload_lds16(gb + k0 + 32,          &Bl[nxt][lofs]);
            gload_lds16(gb + k0 + 32 + 16 * K, &Bl[nxt][lofs + 512]);
        }
        bf16x8 af[4], bfr[4];
        #pragma unroll
        for (int m = 0; m < 4; m++)
            af[m] = *(const bf16x8*)(&Al[cur][(wm + m * 16 + l15) * 32 + rc]);
        #pragma unroll
        for (int n = 0; n < 4; n++)
            bfr[n] = *(const bf16x8*)(&Bl[cur][(wn + n * 16 + l15) * 32 + rc]);
        __builtin_amdgcn_s_setprio(1);
        #pragma unroll
        for (int m = 0; m < 4; m++)
            #pragma unroll
            for (int n = 0; n < 4; n++)
                acc[m][n] = __builtin_amdgcn_mfma_f32_16x16x32_bf16(af[m], bfr[n], acc[m][n], 0, 0, 0);
        __builtin_amdgcn_s_setprio(0);
        __syncthreads();   // drains next-tile loads (they overlapped compute)
        cur = nxt;
    }

    #pragma unroll
    for (int n = 0; n < 4; n++) {
        int col = n0 + wn + n * 16 + l15;
        float bv = bias[col];
        int which = col >> 10;          // 0=Q 1=K 2=V
        int d = col & 1023;
        int h = d >> 6, hd = d & 63;
        #pragma unroll
        for (int m = 0; m < 4; m++) {
            #pragma unroll
            for (int j = 0; j < 4; j++) {
                int row = m0 + wm + m * 16 + lhi * 4 + j;
                int b = row >> 11, t = row & 2047;
                float val = acc[m][n][j] + bv;
                int bh = b * 16 + h;
                if (which == 0)      q_ws[(bh * 2048 + t) * 64 + hd] = f2bf(val * QSC);
                else if (which == 1) k_ws[(bh * 2048 + t) * 64 + hd] = f2bf(val);
                else                 vT_ws[(bh * 64 + hd) * 2048 + t] = f2bf(val);
            }
        }
    }
}

// ---------------- Flash attention (causal) ----------------
#define LKK 72

__global__ __launch_bounds__(512, 4)
void attn_fwd(const unsigned short* __restrict__ q_ws,
              const unsigned short* __restrict__ k_ws,
              const unsigned short* __restrict__ vT_ws,
              unsigned short* __restrict__ attn_ws)
{
    __shared__ unsigned short Kb[2][64 * LKK];
    __shared__ unsigned short Vb[2][64 * LKK];
    __shared__ unsigned short Pl[8][16 * 64];

    const int bh = blockIdx.x;
    const int p  = blockIdx.y;
    const int b = bh >> 4, h = bh & 15;
    const int tid = threadIdx.x;
    const int lane = tid & 63, wid = tid >> 6;
    const int l15 = lane & 15, lhi = lane >> 4;
    const int tbase = bh * 2048;
    const float NINF = -__builtin_inff();

    const int r0 = tid >> 3;
    const int c0 = (tid & 7) * 8;
    const unsigned short* kg = k_ws + (size_t)(tbase + r0) * 64 + c0;
    const unsigned short* vg = vT_ws + ((size_t)bh * 64 + r0) * 2048 + c0;

    unsigned short* Pw = &Pl[wid][0];
    const int xr = l15 & 7;

    #pragma unroll 1
    for (int seg = 0; seg < 2; ++seg) {
        const int qb = seg ? p : 15 - p;
        const int q0 = qb * 128;
        const int qrow = q0 + wid * 16;
        const int nkv = 2 * (qb + 1);

        bf16x8 qf[2];
        #pragma unroll
        for (int ks = 0; ks < 2; ks++)
            qf[ks] = *(const bf16x8*)(q_ws + (size_t)(tbase + qrow + l15) * 64 + ks * 32 + lhi * 8);

        f32x4 o[4] = {};
        float mreg = NINF, lst = 0.f;

        {
            uint4 ka = *(const uint4*)(kg);
            uint4 va = *(const uint4*)(vg);
            *(uint4*)(&Kb[0][r0 * LKK + c0]) = ka;
            *(uint4*)(&Vb[0][r0 * LKK + c0]) = va;
        }
        __syncthreads();

        int cur = 0;
        for (int kb = 0; kb < nkv; ++kb) {
            const int k0 = kb * 64;
            const int knx = (kb + 1 < nkv ? kb + 1 : kb) * 64;
            uint4 ka = *(const uint4*)(kg + (size_t)knx * 64);
            uint4 va = *(const uint4*)(vg + knx);

            if (k0 <= qrow + 15) {
                f32x4 s[4] = {};
                __builtin_amdgcn_s_setprio(1);
                #pragma unroll
                for (int ks = 0; ks < 2; ks++) {
                    bf16x8 kf[4];
                    #pragma unroll
                    for (int n = 0; n < 4; n++)
                        kf[n] = *(const bf16x8*)(&Kb[cur][(n * 16 + l15) * LKK + ks * 32 + lhi * 8]);
                    #pragma unroll
                    for (int n = 0; n < 4; n++)
                        s[n] = __builtin_amdgcn_mfma_f32_16x16x32_bf16(kf[n], qf[ks], s[n], 0, 0, 0);
                }
                __builtin_amdgcn_s_setprio(0);
                if (k0 + 63 > qrow) {
                    int qg = qrow + l15;
                    #pragma unroll
                    for (int n = 0; n < 4; n++) {
                        int kgl = k0 + n * 16 + lhi * 4;
                        #pragma unroll
                        for (int j = 0; j < 4; j++)
                            s[n][j] = (kgl + j <= qg) ? s[n][j] : NINF;
                    }
                }
                float mx = NINF;
                #pragma unroll
                for (int n = 0; n < 4; n++)
                    #pragma unroll
                    for (int j = 0; j < 4; j++)
                        mx = fmaxf(mx, s[n][j]);
                mx = fmaxf(mx, __shfl_xor(mx, 16));
                mx = fmaxf(mx, __shfl_xor(mx, 32));

                if (__all(mx <= mreg + 8.f)) {
                    float rs = 0.f;
                    #pragma unroll
                    for (int n = 0; n < 4; n++)
                        #pragma unroll
                        for (int j = 0; j < 4; j++) {
                            float pv = exp2f(s[n][j] - mreg);
                            s[n][j] = pv;
                            rs += pv;
                        }
                    rs += __shfl_xor(rs, 16);
                    rs += __shfl_xor(rs, 32);
                    lst += rs;
                } else {
                    float mnew = fmaxf(mreg, mx);
                    float al = exp2f(mreg - mnew);
                    mreg = mnew;
                    float rs = 0.f;
                    #pragma unroll
                    for (int n = 0; n < 4; n++)
                        #pragma unroll
                        for (int j = 0; j < 4; j++) {
                            float pv = exp2f(s[n][j] - mnew);
                            s[n][j] = pv;
                            rs += pv;
                        }
                    rs += __shfl_xor(rs, 16);
                    rs += __shfl_xor(rs, 32);
                    lst = lst * al + rs;
                    #pragma unroll
                    for (int j = 0; j < 4; j++) {
                        float a = __shfl(al, lhi * 4 + j);
                        #pragma unroll
                        for (int nd = 0; nd < 4; nd++)
                            o[nd][j] *= a;
                    }
                }
                #pragma unroll
                for (int n = 0; n < 4; n++) {
                    ushort4 pk;
                    pk.x = bfc(s[n][0]); pk.y = bfc(s[n][1]);
                    pk.z = bfc(s[n][2]); pk.w = bfc(s[n][3]);
                    int chunk = (2 * n + (lhi >> 1)) ^ xr;
                    *(ushort4*)(&Pw[l15 * 64 + chunk * 8 + (lhi & 1) * 4]) = pk;
                }
                __builtin_amdgcn_s_setprio(1);
                #pragma unroll
                for (int ks = 0; ks < 2; ks++) {
                    int chunk = (4 * ks + lhi) ^ xr;
                    bf16x8 pf = *(const bf16x8*)(&Pw[l15 * 64 + chunk * 8]);
                    bf16x8 vf[4];
                    #pragma unroll
                    for (int nd = 0; nd < 4; nd++)
                        vf[nd] = *(const bf16x8*)(&Vb[cur][(nd * 16 + l15) * LKK + ks * 32 + lhi * 8]);
                    #pragma unroll
                    for (int nd = 0; nd < 4; nd++)
                        o[nd] = __builtin_amdgcn_mfma_f32_16x16x32_bf16(pf, vf[nd], o[nd], 0, 0, 0);
                }
                __builtin_amdgcn_s_setprio(0);
            }
            *(uint4*)(&Kb[cur ^ 1][r0 * LKK + c0]) = ka;
            *(uint4*)(&Vb[cur ^ 1][r0 * LKK + c0]) = va;
            __syncthreads();
            cur ^= 1;
        }
        #pragma unroll
        for (int j = 0; j < 4; j++) {
            float lv = __shfl(lst, lhi * 4 + j);
            float inv = 1.0f / lv;
            int t = qrow + lhi * 4 + j;
            #pragma unroll
            for (int nd = 0; nd < 4; nd++) {
                int d = nd * 16 + l15;
                attn_ws[((size_t)(b * 2048 + t) * 16 + h) * 64 + d] = f2bf(o[nd][j] * inv);
            }
        }
    }
}

// ---------------- Output projection GEMM (2-phase + granule swizzle) ----------------
__global__ __launch_bounds__(256)
void proj_gemm2(const unsigned short* __restrict__ A,
                const unsigned short* __restrict__ Bt,
                const float* __restrict__ bias, float* __restrict__ out)
{
    const int K = 1024, N = 1024;
    __shared__ unsigned short Al[2][128 * 32];
    __shared__ unsigned short Bl[2][128 * 32];
    const int tid = threadIdx.x;
    const int lane = tid & 63, w = tid >> 6;
    const int l15 = lane & 15, lhi = lane >> 4;
    const int m0 = blockIdx.x * 128, n0 = blockIdx.y * 128;
    const int wm = (w >> 1) * 64, wn = (w & 1) * 64;

    const int srow = w * 32 + (lane >> 2);
    const int sg = ((lane & 3) ^ ((lane >> 3) & 3)) * 8;
    const unsigned short* ga = A + (size_t)(m0 + srow) * K + sg;
    const unsigned short* gb = Bt + (size_t)(n0 + srow) * K + sg;
    const int lofs = w * 32 * 32;

    const int rc = (lhi ^ ((l15 >> 1) & 3)) * 8;

    f32x4 acc[4][4] = {};

    gload_lds16(ga, &Al[0][lofs]);
    gload_lds16(ga + 16 * K, &Al[0][lofs + 512]);
    gload_lds16(gb, &Bl[0][lofs]);
    gload_lds16(gb + 16 * K, &Bl[0][lofs + 512]);
    __syncthreads();

    int cur = 0;
    for (int k0 = 0; k0 < K; k0 += 32) {
        const int nxt = cur ^ 1;
        if (k0 + 32 < K) {
            gload_lds16(ga + k0 + 32,          &Al[nxt][lofs]);
            gload_lds16(ga + k0 + 32 + 16 * K, &Al[nxt][lofs + 512]);
            gload_lds16(gb + k0 + 32,          &Bl[nxt][lofs]);
            gload_lds16(gb + k0 + 32 + 16 * K, &Bl[nxt][lofs + 512]);
        }
        bf16x8 af[4], bfr[4];
        #pragma unroll
        for (int m = 0; m < 4; m++)
            af[m] = *(const bf16x8*)(&Al[cur][(wm + m * 16 + l15) * 32 + rc]);
        #pragma unroll
        for (int n = 0; n < 4; n++)
            bfr[n] = *(const bf16x8*)(&Bl[cur][(wn + n * 16 + l15) * 32 + rc]);
        __builtin_amdgcn_s_setprio(1);
        #pragma unroll
        for (int m = 0; m < 4; m++)
            #pragma unroll
            for (int n = 0; n < 4; n++)
                acc[m][n] = __builtin_amdgcn_mfma_f32_16x16x32_bf16(af[m], bfr[n], acc[m][n], 0, 0, 0);
        __builtin_amdgcn_s_setprio(0);
        __syncthreads();
        cur = nxt;
    }

    #pragma unroll
    for (int n = 0; n < 4; n++) {
        int col = n0 + wn + n * 16 + l15;
        float bv = bias[col];
        #pragma unroll
        for (int m = 0; m < 4; m++)
            #pragma unroll
            for (int j = 0; j < 4; j++) {
                int row = m0 + wm + m * 16 + lhi * 4 + j;
                out[row * N + col] = acc[m][n][j] + bv;
            }
    }
}

extern "C" void kernel_launch(void* const* d_in, const int* in_sizes, int n_in,
                              void* d_out, int out_size, void* d_ws, size_t ws_size,
                              hipStream_t stream)
{
    const float* x      = (const float*)d_in[0];
    const float* w_qkv  = (const float*)d_in[1];
    const float* b_qkv  = (const float*)d_in[2];
    const float* w_proj = (const float*)d_in[3];
    const float* b_proj = (const float*)d_in[4];
    float* out = (float*)d_out;

    const size_t SEG = (size_t)8 * 1024 * 1024;
    unsigned short* q_ws    = (unsigned short*)d_ws;
    unsigned short* k_ws    = q_ws + SEG;
    unsigned short* vT_ws   = k_ws + SEG;
    unsigned short* attn_ws = vT_ws + SEG;

    unsigned short* x_bf   = (unsigned short*)d_out;          // d_out as scratch
    unsigned short* wqkvT  = x_bf + SEG;
    unsigned short* wprojT = q_ws;                            // dead after attn

    cvt_bf16<<<4096, 256, 0, stream>>>(x, x_bf);
    transpose_w<<<dim3(16, 48), 256, 0, stream>>>(w_qkv, wqkvT, 1024, 3072);
    qkv_gemm2<<<dim3(64, 24), 256, 0, stream>>>(x_bf, wqkvT, b_qkv, q_ws, k_ws, vT_ws);
    attn_fwd<<<dim3(64, 8), 512, 0, stream>>>(q_ws, k_ws, vT_ws, attn_ws);
    transpose_w<<<dim3(16, 16), 256, 0, stream>>>(w_proj, wprojT, 1024, 1024);
    proj_gemm2<<<dim3(64, 8), 256, 0, stream>>>(attn_ws, wprojT, b_proj, out);
}